// Round 1
// 1517.742 us; speedup vs baseline: 2.3458x; 2.3458x over previous
//
#include <hip/hip_runtime.h>

#define BB 512
#define TT 1024
#define HH 100
#define HP 112
#define VV 62
#define BTV (512*1024*62)

// ws float offsets (buf = ws[0 .. 52428800) = [T][B][H] fp32)
#define OFF_EP  52428800   // 62*100 ep table (emb@Wi0^T + b0)
#define OFF_WP  52435000   // padded unit weights [5][100][112]: Wh0,Wi1,Wh1,Wi2,Wh2
#define OFF_BS  52491000   // bias sums layers 1,2: [2][100]
#define OFF_WDT 52491200   // W_dec transposed+padded: [100][64]
#define OFF_BDP 52497600   // b_dec padded to 64

__device__ inline float tanh_fast(float x){
  float ax = fabsf(x);
  float e  = __expf(2.0f*ax);
  float r  = 1.0f - __fdividef(2.0f, e + 1.0f);
  return copysignf(r, x);
}

__global__ void prep_kernel(
    const float* __restrict__ emb, const float* __restrict__ W_ih,
    const float* __restrict__ W_hh,
    const float* __restrict__ b_ih, const float* __restrict__ b_hh,
    const float* __restrict__ W_dec, const float* __restrict__ b_dec,
    float* __restrict__ ws)
{
  int g = blockIdx.x*256 + threadIdx.x;
  if (g < 6200){
    int v = g/100, k = g%100;
    float a = b_ih[k] + b_hh[k];
    const float* er = emb + v*100;
    const float* wr = W_ih + k*100;
    for (int h=0; h<100; h++) a = fmaf(er[h], wr[h], a);
    ws[OFF_EP + v*100 + k] = a;
  } else if (g < 62200){
    int i = g - 6200;
    int u = i/11200, r = i%11200;
    int k = r/112, h = r%112;
    int l = (u+1)>>1;                       // u: 0->Wh0, 1->Wi1, 2->Wh1, 3->Wi2, 4->Wh2
    const float* src = (u & 1) ? W_ih : W_hh;
    ws[OFF_WP + i] = (h < HH) ? src[l*10000 + k*100 + h] : 0.f;
  } else if (g < 62400){
    int i = g - 62200;
    int l = i/100 + 1, k = i%100;
    ws[OFF_BS + i] = b_ih[l*100+k] + b_hh[l*100+k];
  } else if (g < 68800){
    int i = g - 62400;
    int h = i/64, v = i%64;
    ws[OFF_WDT + i] = (v < VV) ? W_dec[v*100 + h] : 0.f;
  } else if (g < 68864){
    int i = g - 68800;
    ws[OFF_BDP + i] = (i < VV) ? b_dec[i] : 0.f;
  }
}

#define BARRIER() do{ asm volatile("s_waitcnt lgkmcnt(0)" ::: "memory"); \
                      __builtin_amdgcn_s_barrier(); \
                      asm volatile("" ::: "memory"); }while(0)

// Fused 3-layer pipelined recurrence. 256 WGs x 512 thr; WG handles rows (b, b+256).
// 5 matvec units of 100 lanes: u0=Wh0, u1=Wi1, u2=Wh1, u3=Wi2, u4=Wh2.
// Lane L=4o+sq of a unit: rows 4o..4o+3, col segment 28sq..28sq+27 (H padded to 112).
// Butterfly reduce leaves lane 4o+sq with total z[4o+sq]. Wavefront schedule:
// step s computes h0[s], h1[s-1], h2[s-2]. No in-loop global loads; stores fire-and-forget.
__global__ __launch_bounds__(512, 2) void fused_rnn(
    const int* __restrict__ ids, const float* __restrict__ ws,
    float* __restrict__ buf, float* __restrict__ hid)
{
  __shared__ float ep_s[6200];
  __shared__ int   ids_s[2][TT];
  __shared__ float hs[2][3][HP];     // [row][layer][padded H]
  __shared__ float zz[2][2][HH];     // [row][{Wh1,Wh2} outputs]

  const int tid = threadIdx.x;
  const int bA = blockIdx.x;
  const int bB = blockIdx.x + 256;

  int u = tid / 100;
  int L = tid - u*100;
  const bool act = (tid < 500);
  if (!act){ u = 4; L = 99; }        // clamp idle lanes; their writes are masked below
  const int o4 = (L & ~3);
  const int sq = L & 3;
  const bool is_b0 = (L & 1);
  const bool is_b1 = (L & 2);

  // weight fragments: 4 rows x 7 float4 (28 cols)
  float4 w[4][7];
  #pragma unroll
  for (int j=0;j<4;j++){
    const float4* wr = (const float4*)(ws + OFF_WP + u*11200 + (o4+j)*HP + 28*sq);
    #pragma unroll
    for (int i=0;i<7;i++) w[j][i] = wr[i];
  }
  // bias folded into acc init, added once per quad (sq==0 lane only)
  float binit[4] = {0.f,0.f,0.f,0.f};
  if ((u==1 || u==3) && sq==0){
    const float* bsrow = ws + OFF_BS + (u==3 ? 100 : 0);
    #pragma unroll
    for (int j=0;j<4;j++) binit[j] = bsrow[o4+j];
  }

  for (int i=tid;i<6200;i+=512) ep_s[i] = ws[OFF_EP+i];
  for (int i=tid;i<TT;i+=512){
    ids_s[0][i] = ids[(size_t)bA*TT + i];
    ids_s[1][i] = ids[(size_t)bB*TT + i];
  }
  for (int i=tid;i<2*3*HP;i+=512) ((float*)hs)[i] = 0.f;
  __syncthreads();

  const int lin = (u<=1) ? 0 : (u<=3 ? 1 : 2);   // input layer per unit
  const float* hinA = &hs[0][lin][28*sq];
  const float* hinB = &hs[1][lin][28*sq];

  int idnA = ids_s[0][1], idnB = ids_s[1][1];
  float epxA = ep_s[ids_s[0][0]*HH + L];
  float epxB = ep_s[ids_s[1][0]*HH + L];
  float epxA_n = 0.f, epxB_n = 0.f;

  float* stA = buf + (size_t)bA*HH + L;
  float* stB = buf + (size_t)bB*HH + L;

  auto quad_reduce = [&](float a0,float a1,float a2,float a3)->float{
    float sA = is_b0 ? a0 : a1, kA = is_b0 ? a1 : a0;
    float A  = kA + __shfl_xor(sA, 1);
    float sB = is_b0 ? a2 : a3, kB = is_b0 ? a3 : a2;
    float Bq = kB + __shfl_xor(sB, 1);
    float sC = is_b1 ? A : Bq, kC = is_b1 ? Bq : A;
    return kC + __shfl_xor(sC, 2);
  };

  for (int s=0; s<TT+2; ++s){
    // ---------- phase A: 5 matvecs (both rows) ----------
    float aA0=binit[0], aA1=binit[1], aA2=binit[2], aA3=binit[3];
    float aB0=binit[0], aB1=binit[1], aB2=binit[2], aB3=binit[3];
    #pragma unroll
    for (int i=0;i<7;i++){
      float4 ha = ((const float4*)hinA)[i];
      float4 hb = ((const float4*)hinB)[i];
      float4 w0=w[0][i], w1=w[1][i], w2=w[2][i], w3=w[3][i];
      aA0=fmaf(ha.x,w0.x,aA0); aA0=fmaf(ha.y,w0.y,aA0); aA0=fmaf(ha.z,w0.z,aA0); aA0=fmaf(ha.w,w0.w,aA0);
      aA1=fmaf(ha.x,w1.x,aA1); aA1=fmaf(ha.y,w1.y,aA1); aA1=fmaf(ha.z,w1.z,aA1); aA1=fmaf(ha.w,w1.w,aA1);
      aA2=fmaf(ha.x,w2.x,aA2); aA2=fmaf(ha.y,w2.y,aA2); aA2=fmaf(ha.z,w2.z,aA2); aA2=fmaf(ha.w,w2.w,aA2);
      aA3=fmaf(ha.x,w3.x,aA3); aA3=fmaf(ha.y,w3.y,aA3); aA3=fmaf(ha.z,w3.z,aA3); aA3=fmaf(ha.w,w3.w,aA3);
      aB0=fmaf(hb.x,w0.x,aB0); aB0=fmaf(hb.y,w0.y,aB0); aB0=fmaf(hb.z,w0.z,aB0); aB0=fmaf(hb.w,w0.w,aB0);
      aB1=fmaf(hb.x,w1.x,aB1); aB1=fmaf(hb.y,w1.y,aB1); aB1=fmaf(hb.z,w1.z,aB1); aB1=fmaf(hb.w,w1.w,aB1);
      aB2=fmaf(hb.x,w2.x,aB2); aB2=fmaf(hb.y,w2.y,aB2); aB2=fmaf(hb.z,w2.z,aB2); aB2=fmaf(hb.w,w2.w,aB2);
      aB3=fmaf(hb.x,w3.x,aB3); aB3=fmaf(hb.y,w3.y,aB3); aB3=fmaf(hb.z,w3.z,aB3); aB3=fmaf(hb.w,w3.w,aB3);
    }
    float zA = quad_reduce(aA0,aA1,aA2,aA3);
    float zB = quad_reduce(aB0,aB1,aB2,aB3);

    // prefetch next-step ep rows + ids (unit 0 only; LDS-only)
    if (u==0){
      epxA_n = ep_s[idnA*HH + L];
      epxB_n = ep_s[idnB*HH + L];
      int nid = (s+2 < TT) ? s+2 : TT-1;
      idnA = ids_s[0][nid]; idnB = ids_s[1][nid];
    }
    if (u==2){        zz[0][0][L] = zA; zz[1][0][L] = zB; }
    if (u==4 && act){ zz[0][1][L] = zA; zz[1][1][L] = zB; }
    BARRIER();

    // ---------- phase B: combine + state handoff ----------
    if (u==0 && s < TT){                       // h0[s]
      float hA = tanh_fast(epxA + zA);
      float hB = tanh_fast(epxB + zB);
      hs[0][0][L] = hA; hs[1][0][L] = hB;
      epxA = epxA_n; epxB = epxB_n;
    }
    if (u==1 && (unsigned)(s-1) < TT){         // h1[s-1]
      hs[0][1][L] = tanh_fast(zA + zz[0][0][L]);
      hs[1][1][L] = tanh_fast(zB + zz[1][0][L]);
    }
    if (u==3 && s >= 2){                       // h2[s-2] + global store
      float hA = tanh_fast(zA + zz[0][1][L]);
      float hB = tanh_fast(zB + zz[1][1][L]);
      hs[0][2][L] = hA; hs[1][2][L] = hB;
      *stA = hA; *stB = hB;
      stA += BB*HH; stB += BB*HH;
    }
    BARRIER();
  }
  __syncthreads();

  if (tid < 300){
    int l = tid/100, k = tid - l*100;
    hid[((size_t)l*BB + bA)*HH + k] = hs[0][l][k];
    hid[((size_t)l*BB + bB)*HH + k] = hs[1][l][k];
  }
}

// Decoder: WG = (b, 128 consecutive t). Output-coalesced. acc over 64 (padded) vocab.
__global__ __launch_bounds__(128) void dec_kernel(
    const float* __restrict__ buf, const float* __restrict__ wdt,
    const float* __restrict__ bdp, float* __restrict__ out)
{
  __shared__ float rt[100*129];
  const int tid = threadIdx.x;
  const int wg  = blockIdx.x;
  const int bb  = wg >> 3;
  const int t0  = (wg & 7) * 128;
  const float4* b4 = (const float4*)buf;

  #pragma unroll
  for (int j=0;j<25;j++){
    int f = j*128 + tid;
    int i = f/25, c = f%25;
    float4 v = b4[((size_t)(t0+i)*BB + bb)*25 + c];
    rt[(4*c+0)*129 + i] = v.x;
    rt[(4*c+1)*129 + i] = v.y;
    rt[(4*c+2)*129 + i] = v.z;
    rt[(4*c+3)*129 + i] = v.w;
  }
  __syncthreads();

  float4 acc[16];
  const float4* bd4 = (const float4*)bdp;
  #pragma unroll
  for (int j=0;j<16;j++) acc[j] = bd4[j];

  for (int h=0; h<HH; h++){
    float rv = rt[h*129 + tid];
    const float4* w4 = (const float4*)(wdt + h*64);
    #pragma unroll
    for (int j=0;j<16;j++){
      float4 w = w4[j];
      acc[j].x = fmaf(rv,w.x,acc[j].x);
      acc[j].y = fmaf(rv,w.y,acc[j].y);
      acc[j].z = fmaf(rv,w.z,acc[j].z);
      acc[j].w = fmaf(rv,w.w,acc[j].w);
    }
  }

  float2* o2 = (float2*)(out + (size_t)(wg*128 + tid)*VV);
  #pragma unroll
  for (int j=0;j<15;j++){
    o2[2*j]   = make_float2(acc[j].x, acc[j].y);
    o2[2*j+1] = make_float2(acc[j].z, acc[j].w);
  }
  o2[30] = make_float2(acc[15].x, acc[15].y);   // v=60,61
}

extern "C" void kernel_launch(void* const* d_in, const int* in_sizes, int n_in,
                              void* d_out, int out_size, void* d_ws, size_t ws_size,
                              hipStream_t stream)
{
  const int*   ids   = (const int*)d_in[0];
  const float* emb   = (const float*)d_in[1];
  const float* W_ih  = (const float*)d_in[2];
  const float* W_hh  = (const float*)d_in[3];
  const float* b_ih  = (const float*)d_in[4];
  const float* b_hh  = (const float*)d_in[5];
  const float* W_dec = (const float*)d_in[6];
  const float* b_dec = (const float*)d_in[7];
  float* out = (float*)d_out;
  float* ws  = (float*)d_ws;
  float* buf = ws;                 // [T][B][H] fp32, ~210 MB
  float* hid = out + BTV;

  prep_kernel<<<269, 256, 0, stream>>>(emb, W_ih, W_hh, b_ih, b_hh, W_dec, b_dec, ws);
  fused_rnn <<<256, 512, 0, stream>>>(ids, ws, buf, hid);
  dec_kernel<<<4096, 128, 0, stream>>>(buf, ws+OFF_WDT, ws+OFF_BDP, out);
}

// Round 2
// 1369.245 us; speedup vs baseline: 2.6002x; 1.1085x over previous
//
#include <hip/hip_runtime.h>

#define BB 512
#define TT 1024
#define HH 100
#define VV 62
#define BTV (512*1024*62)

// ws float offsets (buf = ws[0 .. 52428800) = [B][T][H] fp32)
#define OFF_EP  52428800   // 62*100 ep table (emb@Wi0^T + b0)   [6200]
#define OFF_WU  52435200   // unit weights: u0 100*112, u1 200*112, u2 200*112  [56000]
#define OFF_BS  52491200   // bias sums layers 1,2: [2][100]
#define OFF_WDT 52491400   // W_dec transposed+padded: [100][64]
#define OFF_BDP 52497800   // b_dec padded to 64

typedef float v2f __attribute__((ext_vector_type(2)));

__device__ inline float tanh_fast(float x){
  float ax = fabsf(x);
  float e  = __expf(2.0f*ax);
  float r  = 1.0f - __fdividef(2.0f, e + 1.0f);
  return copysignf(r, x);
}

__device__ inline float dpp_xor1(float x){
  return __int_as_float(__builtin_amdgcn_update_dpp(0, __float_as_int(x), 0xB1, 0xF, 0xF, true));
}
__device__ inline float dpp_xor2(float x){
  return __int_as_float(__builtin_amdgcn_update_dpp(0, __float_as_int(x), 0x4E, 0xF, 0xF, true));
}

__global__ void prep_kernel(
    const float* __restrict__ emb, const float* __restrict__ W_ih,
    const float* __restrict__ W_hh,
    const float* __restrict__ b_ih, const float* __restrict__ b_hh,
    const float* __restrict__ W_dec, const float* __restrict__ b_dec,
    float* __restrict__ ws)
{
  int g = blockIdx.x*256 + threadIdx.x;
  if (g < 6200){
    int v = g/100, k = g%100;
    float a = b_ih[k] + b_hh[k];
    const float* er = emb + v*100;
    const float* wr = W_ih + k*100;
    for (int h=0; h<100; h++) a = fmaf(er[h], wr[h], a);
    ws[OFF_EP + v*100 + k] = a;
  } else if (g < 62200){
    int i = g - 6200;
    int u, base;
    if (i < 11200){ u=0; base=i; }
    else if (i < 33600){ u=1; base=i-11200; }
    else { u=2; base=i-33600; }
    int lane = base/112, e = base%112;
    int j = e/56, c = e%56;
    float val;
    if (u==0){
      int q = lane&1, rp = lane>>1;
      int r = rp + 50*j;
      int col = 56*q + c;
      val = (col < HH) ? W_hh[r*HH + col] : 0.f;
    } else {
      int q = lane&3, rp = lane>>2;
      int r = rp + 50*j;
      if (q < 2){
        int col = 56*q + c;
        val = (col < HH) ? W_ih[u*10000 + r*HH + col] : 0.f;
      } else {
        int col = 56*(q-2) + c;
        val = (col < HH) ? W_hh[u*10000 + r*HH + col] : 0.f;
      }
    }
    ws[OFF_WU + i] = val;
  } else if (g < 62400){
    int i = g - 62200;
    int l = i/100 + 1, k = i%100;
    ws[OFF_BS + i] = b_ih[l*100+k] + b_hh[l*100+k];
  } else if (g < 68800){
    int i = g - 62400;
    int h = i/64, v = i%64;
    ws[OFF_WDT + i] = (v < VV) ? W_dec[v*100 + h] : 0.f;
  } else if (g < 68864){
    int i = g - 68800;
    ws[OFF_BDP + i] = (i < VV) ? b_dec[i] : 0.f;
  }
}

// Fused 3-layer pipelined recurrence, merged-unit form.
// u0 (tid 0-99):   L0, lane l: q=l&1, rp=l>>1, rows {rp,rp+50}, cols [56q,56q+56) of Wh0.
// u1 (tid 100-299): L1, lane l: q=l&3, rp=l>>2, rows {rp,rp+50}; q<2 -> Wi1 cols 56(q),
//                   q>=2 -> Wh1 cols 56(q-2). 4-way col split over [Wi1|Wh1].
// u2 (tid 300-499): L2, same with Wi2/Wh2.
// All units read h parity (s+1)&1, write parity s&1 -> ONE barrier per step.
// Step s computes h0[s], h1[s-1], h2[s-2]. Stores are fire-and-forget (vmcnt never drained).
__global__ __launch_bounds__(512, 2) void fused_rnn(
    const int* __restrict__ ids, const float* __restrict__ ws,
    float* __restrict__ buf, float* __restrict__ hid)
{
  __shared__ float ep_s[6200];
  __shared__ int   ids_s[2][TT];
  __shared__ float hs[2][2][3][112];   // [parity][batchRow][layer][paddedH]

  const int tid = threadIdx.x;
  const int bA = blockIdx.x, bB = blockIdx.x + 256;

  int u, l; bool act = true;
  if (tid < 100){ u=0; l=tid; }
  else if (tid < 300){ u=1; l=tid-100; }
  else if (tid < 500){ u=2; l=tid-300; }
  else { u=2; l=199; act=false; }

  int q, rp, lv, col0;
  if (u==0){ q = l&1; rp = l>>1; lv = 0; col0 = 56*q; }
  else     { q = l&3; rp = l>>2; lv = (u==1) ? ((q<2)?0:1) : ((q<2)?1:2); col0 = 56*(q&1); }

  // per-lane weights: 112 floats = 56 v2f (kept in VGPRs; all indices compile-time)
  v2f w[56];
  {
    int ubase = (u==0) ? 0 : (u==1) ? 11200 : 33600;
    const float4* ws4 = (const float4*)(ws + OFF_WU + ubase + l*112);
    #pragma unroll
    for (int i=0;i<28;i++){
      float4 t = ws4[i];
      w[2*i]   = (v2f){t.x, t.y};
      w[2*i+1] = (v2f){t.z, t.w};
    }
  }
  float bias0 = 0.f, bias1 = 0.f;
  if (u != 0 && q == 0){
    const float* bs = ws + OFF_BS + (u-1)*100;
    bias0 = bs[rp]; bias1 = bs[rp+50];
  }

  for (int i=tid;i<6200;i+=512) ep_s[i] = ws[OFF_EP+i];
  for (int i=tid;i<TT;i+=512){
    ids_s[0][i] = ids[(size_t)bA*TT + i];
    ids_s[1][i] = ids[(size_t)bB*TT + i];
  }
  for (int i=tid;i<2*2*3*112;i+=512) ((float*)hs)[i] = 0.f;
  __syncthreads();

  // read bases (float4 units). parity block stride = 2*3*28 = 168 float4.
  const float4* h4 = (const float4*)hs;
  const int c4 = col0 >> 2;
  const int iA = (0*3 + lv)*28 + c4;
  const int iB = (1*3 + lv)*28 + c4;
  float* hw = (float*)hs;              // write: [(p*2+X)*3+lay]*112 + r

  // unit0 ep state
  int idn = 0; float epx0 = 0.f, epx1 = 0.f;
  if (u == 0){
    int id0 = ids_s[q][0];
    epx0 = ep_s[id0*HH + rp];
    epx1 = ep_s[id0*HH + rp+50];
    idn  = ids_s[q][1];
  }
  const int X  = q >> 1;               // epilogue batch (u1/u2)
  const int rr = rp + 50*(q & 1);      // epilogue row   (u1/u2)
  float* stp = buf + ((size_t)(X ? bB : bA))*TT*HH + rr;   // [B][T][H]

  for (int s = 0; s < TT + 2; ++s){
    const int po = (s & 1) ? 0 : 168;        // read parity offset (float4)
    const int wo = (s & 1) ? 672 : 0;        // write parity offset (float)

    v2f aA0 = {bias0, 0.f}, aA1 = {bias1, 0.f};
    v2f aB0 = {bias0, 0.f}, aB1 = {bias1, 0.f};
    #pragma unroll
    for (int i=0;i<14;i++){
      float4 ha = h4[iA + po + i];
      float4 hb = h4[iB + po + i];
      v2f h0 = {ha.x, ha.y}, h1 = {ha.z, ha.w};
      v2f g0 = {hb.x, hb.y}, g1 = {hb.z, hb.w};
      aA0 = __builtin_elementwise_fma(w[2*i],    h0, aA0);
      aA0 = __builtin_elementwise_fma(w[2*i+1],  h1, aA0);
      aA1 = __builtin_elementwise_fma(w[28+2*i], h0, aA1);
      aA1 = __builtin_elementwise_fma(w[29+2*i], h1, aA1);
      aB0 = __builtin_elementwise_fma(w[2*i],    g0, aB0);
      aB0 = __builtin_elementwise_fma(w[2*i+1],  g1, aB0);
      aB1 = __builtin_elementwise_fma(w[28+2*i], g0, aB1);
      aB1 = __builtin_elementwise_fma(w[29+2*i], g1, aB1);
    }
    float zA0 = aA0.x + aA0.y;
    float zA1 = aA1.x + aA1.y;
    float zB0 = aB0.x + aB0.y;
    float zB1 = aB1.x + aB1.y;
    zA0 += dpp_xor1(zA0); zA1 += dpp_xor1(zA1);
    zB0 += dpp_xor1(zB0); zB1 += dpp_xor1(zB1);
    if (u){
      zA0 += dpp_xor2(zA0); zA1 += dpp_xor2(zA1);
      zB0 += dpp_xor2(zB0); zB1 += dpp_xor2(zB1);
    }

    if (u == 0){
      if (s < TT){
        float za = q ? zB0 : zA0;
        float zb = q ? zB1 : zA1;
        float h0v = tanh_fast(epx0 + za);
        float h1v = tanh_fast(epx1 + zb);
        hw[wo + (q*3 + 0)*112 + rp]      = h0v;
        hw[wo + (q*3 + 0)*112 + rp + 50] = h1v;
        if (s == TT-1){
          int bX = q ? bB : bA;
          hid[(size_t)bX*HH + rp]      = h0v;
          hid[(size_t)bX*HH + rp + 50] = h1v;
        }
        epx0 = ep_s[idn*HH + rp];
        epx1 = ep_s[idn*HH + rp + 50];
        idn  = ids_s[q][(s+2 < TT) ? s+2 : TT-1];
      }
    } else {
      float zs = (q & 1) ? (X ? zB1 : zA1) : (X ? zB0 : zA0);
      bool on = (u == 1) ? ((unsigned)(s-1) < TT) : (s >= 2);
      if (on & act){
        float hv = tanh_fast(zs);
        hw[wo + (X*3 + u)*112 + rr] = hv;
        if (u == 2){ *stp = hv; stp += HH; }
        int bX = X ? bB : bA;
        if (u == 1 && s == TT)     hid[((size_t)BB   + bX)*HH + rr] = hv;
        if (u == 2 && s == TT+1)   hid[((size_t)2*BB + bX)*HH + rr] = hv;
      }
    }

    asm volatile("s_waitcnt lgkmcnt(0)" ::: "memory");
    __builtin_amdgcn_s_barrier();
    asm volatile("" ::: "memory");
  }
}

// Decoder: WG = (b, 128 consecutive t). buf is [B][T][H] -> fully linear reads.
__global__ __launch_bounds__(128) void dec_kernel(
    const float* __restrict__ buf, const float* __restrict__ wdt,
    const float* __restrict__ bdp, float* __restrict__ out)
{
  __shared__ float rt[100*129];
  const int tid = threadIdx.x;
  const int wg  = blockIdx.x;
  const int bb  = wg >> 3;
  const int t0  = (wg & 7) * 128;
  const float4* b4 = (const float4*)buf;
  const size_t rb = ((size_t)bb*TT + t0)*25;

  #pragma unroll
  for (int j=0;j<25;j++){
    int f = j*128 + tid;
    int i = f/25, c = f%25;
    float4 v = b4[rb + f];
    rt[(4*c+0)*129 + i] = v.x;
    rt[(4*c+1)*129 + i] = v.y;
    rt[(4*c+2)*129 + i] = v.z;
    rt[(4*c+3)*129 + i] = v.w;
  }
  __syncthreads();

  float4 acc[16];
  const float4* bd4 = (const float4*)bdp;
  #pragma unroll
  for (int j=0;j<16;j++) acc[j] = bd4[j];

  for (int h=0; h<HH; h++){
    float rv = rt[h*129 + tid];
    const float4* w4 = (const float4*)(wdt + h*64);
    #pragma unroll
    for (int j=0;j<16;j++){
      float4 w = w4[j];
      acc[j].x = fmaf(rv,w.x,acc[j].x);
      acc[j].y = fmaf(rv,w.y,acc[j].y);
      acc[j].z = fmaf(rv,w.z,acc[j].z);
      acc[j].w = fmaf(rv,w.w,acc[j].w);
    }
  }

  // out stays [B][T][V]; (wg,tid) maps to (bb, t0+tid) = row bb*TT + t0 + tid
  float2* o2 = (float2*)(out + ((size_t)bb*TT + t0 + tid)*VV);
  #pragma unroll
  for (int j=0;j<15;j++){
    o2[2*j]   = make_float2(acc[j].x, acc[j].y);
    o2[2*j+1] = make_float2(acc[j].z, acc[j].w);
  }
  o2[30] = make_float2(acc[15].x, acc[15].y);   // v=60,61
}

extern "C" void kernel_launch(void* const* d_in, const int* in_sizes, int n_in,
                              void* d_out, int out_size, void* d_ws, size_t ws_size,
                              hipStream_t stream)
{
  const int*   ids   = (const int*)d_in[0];
  const float* emb   = (const float*)d_in[1];
  const float* W_ih  = (const float*)d_in[2];
  const float* W_hh  = (const float*)d_in[3];
  const float* b_ih  = (const float*)d_in[4];
  const float* b_hh  = (const float*)d_in[5];
  const float* W_dec = (const float*)d_in[6];
  const float* b_dec = (const float*)d_in[7];
  float* out = (float*)d_out;
  float* ws  = (float*)d_ws;
  float* buf = ws;                 // [B][T][H] fp32, ~210 MB
  float* hid = out + BTV;

  prep_kernel<<<269, 256, 0, stream>>>(emb, W_ih, W_hh, b_ih, b_hh, W_dec, b_dec, ws);
  fused_rnn <<<256, 512, 0, stream>>>(ids, ws, buf, hid);
  dec_kernel<<<4096, 128, 0, stream>>>(buf, ws+OFF_WDT, ws+OFF_BDP, out);
}